// Round 16
// baseline (1932.280 us; speedup 1.0000x reference)
//
#include <hip/hip_runtime.h>
#include <cstdint>

#define BB 128
#define DD 512
#define SS 30
#define PP 196
#define TT 12
#define BD (BB*DD)

typedef unsigned short ushortT;
typedef unsigned int uintT;

__device__ __forceinline__ float bf2f(ushortT u)
{
    return __uint_as_float(((uintT)u) << 16);
}
__device__ __forceinline__ ushortT f2bf(float f)
{
    uintT b = __float_as_uint(f);
    return (ushortT)((b + 0x7FFFu + ((b >> 16) & 1u)) >> 16);
}
__device__ __forceinline__ uintT pack2bf(float lo, float hi)
{
    return (uintT)f2bf(lo) | ((uintT)f2bf(hi) << 16);
}

// ---------------------------------------------------------------------------
// Unified small GEMM, bf16 weights: out[m0..m0+8, c0..c0+128) =
// epi( sum_p A_p @ W_p ). block 256 (4 waves, wave = K-split 128/part);
// lane covers 2 cols via one uint load (16 FMA/load); A rows uniform scalar;
// LDS reduce. grid (mblk=M/8, nblk=4, z).
// epi: 0 +bias | 1 sigmoid(+bias) | 4 acc+e1[row,col] | 5 m_sa (A0=m_hist,
//      e1=sattn) | 6 raw | 7 raw -> bf16 store into (ushortT*)out
// ---------------------------------------------------------------------------
struct GDesc {
    const float *A0, *A1;
    const ushortT *W0, *W1;
    const float *bias;
    float *out;
    const float *e1;
    int nparts, epi, mblk, nblk, aux;
};
struct GPack { GDesc d[6]; };

__global__ __launch_bounds__(256)
void gemm4(GPack pk)
{
    GDesc d = pk.d[blockIdx.z];
    if ((int)blockIdx.x >= d.mblk || (int)blockIdx.y >= d.nblk) return;
    const int tid  = threadIdx.x;
    const int lane = tid & 63;
    const int wv   = __builtin_amdgcn_readfirstlane(tid >> 6);

    if (d.epi == 5) {   // m_sa for 2 b's: sum_{tp<=aux} sattn[b,tp]*m_hist[tp,b,:]
        int bb = (blockIdx.x * 4 + blockIdx.y) * 2;
        #pragma unroll
        for (int b = bb; b < bb + 2; ++b) {
            const float* sat = d.e1 + b * 16;
            float a0 = 0.f, a1 = 0.f;
            for (int tp = 0; tp <= d.aux; ++tp) {
                float s = sat[tp];
                const float* mh = d.A0 + (size_t)tp * BD + (size_t)b * DD;
                a0 = fmaf(s, mh[tid], a0);
                a1 = fmaf(s, mh[tid + 256], a1);
            }
            d.out[(size_t)b * DD + tid] = a0;
            d.out[(size_t)b * DD + tid + 256] = a1;
        }
        return;
    }

    const int m0 = blockIdx.x * 8;
    const int c0 = blockIdx.y * 128;
    float accx[8], accy[8];
    #pragma unroll
    for (int m = 0; m < 8; ++m) { accx[m] = 0.f; accy[m] = 0.f; }

    for (int p = 0; p < d.nparts; ++p) {
        const float* A = p ? d.A1 : d.A0;
        const ushortT* W = p ? d.W1 : d.W0;
        const float* a = A + (size_t)m0 * 512 + wv * 128;      // uniform (SGPR)
        const uintT* Wb = (const uintT*)(W + (size_t)(wv * 128) * 512 + c0) + lane;
        #pragma unroll 4
        for (int k = 0; k < 128; ++k) {
            uintT w = Wb[(size_t)k * 256];
            float wx = __uint_as_float(w << 16);
            float wy = __uint_as_float(w & 0xFFFF0000u);
            #pragma unroll
            for (int m = 0; m < 8; ++m) {
                float av = a[m * 512 + k];
                accx[m] = fmaf(av, wx, accx[m]);
                accy[m] = fmaf(av, wy, accy[m]);
            }
        }
    }

    __shared__ float red[4][8][128];
    #pragma unroll
    for (int m = 0; m < 8; ++m)
        *(float2*)&red[wv][m][lane * 2] = make_float2(accx[m], accy[m]);
    __syncthreads();

    for (int i = tid; i < 1024; i += 256) {
        int mm = i >> 7, cl = i & 127;
        float s = (red[0][mm][cl] + red[1][mm][cl])
                + (red[2][mm][cl] + red[3][mm][cl]);
        int row = m0 + mm, col = c0 + cl;
        size_t o = (size_t)row * 512 + col;
        if (d.epi == 0)      d.out[o] = s + d.bias[col];
        else if (d.epi == 1) { float v = s + d.bias[col];
                               d.out[o] = 1.f / (1.f + __expf(-v)); }
        else if (d.epi == 4) d.out[o] = s + d.e1[o];
        else if (d.epi == 7) ((ushortT*)d.out)[o] = f2bf(s);
        else                 d.out[o] = s;
    }
}

// ---------------------------------------------------------------------------
// stepA: blocks 0-127 -> control(t) [t<12]; blocks 128-383 -> gemmD(t-1) [t>0]
// gemmD now FUSES read2: rebuilds ex=softmax(rlog) from rlogp (read1y t-1),
// computes its 2 mnw rows into LDS (wave wv covers d=[wv*64,+64), 196-FMA
// weighted KB dots), then the K=1536 3-seg loop (seg1 A from LDS) + gate.
// ---------------------------------------------------------------------------
struct SP {
    const float *cq, *wca, *bca, *wra, *wwa, *bwa;
    const ushortT *cwsTh;
    float *c_hist, *sattn, *vb;
    const float *msa, *gb, *b2;
    const float *rlogp;
    const ushortT *KBh;
    const ushortT *WamH, *WAH, *WBH;
    float *m_hist, *dst;
    int t;
};

__global__ __launch_bounds__(512)
void stepA(SP P)
{
    const int tid = threadIdx.x;
    const int lane = tid & 63;
    __shared__ float cqw[512], ciw[512];
    __shared__ float clog2[32], cattn[32], slog[16];
    __shared__ float red[8][2][128];
    __shared__ float exsh[2][200];
    __shared__ float mnwsh[2][512];
    __shared__ float wred[4];

    if ((int)blockIdx.x < 128) {
        if (P.t >= TT) return;
        int b = blockIdx.x, w = tid >> 6, t = P.t;
        cqw[tid] = P.cq[(size_t)b*DD + tid] * P.wca[tid];
        __syncthreads();
        for (int s = w; s < SS; s += 8) {
            const ushortT* row = P.cwsTh + ((size_t)b*SS + s)*DD;
            float a = 0.f;
            #pragma unroll
            for (int j = 0; j < 8; ++j)
                a = fmaf(cqw[lane + 64*j], bf2f(row[lane + 64*j]), a);
            for (int off = 32; off; off >>= 1) a += __shfl_xor(a, off, 64);
            if (lane == 0) clog2[s] = a;
        }
        __syncthreads();
        if (tid < 32) {
            float v = (tid < SS) ? clog2[tid] + P.bca[0] : -1e30f;
            float mx = v;
            for (int off = 16; off; off >>= 1) mx = fmaxf(mx, __shfl_xor(mx, off, 32));
            float e = (tid < SS) ? __expf(v - mx) : 0.f;
            float sm = e;
            for (int off = 16; off; off >>= 1) sm += __shfl_xor(sm, off, 32);
            cattn[tid] = e / sm;
        }
        __syncthreads();
        {   // c_i[d] = sum_s cattn[s] * cwsTh[b][s][d]  (coalesced bf16 rows)
            const ushortT* baseh = P.cwsTh + (size_t)b*SS*DD + tid;
            float acc = 0.f;
            #pragma unroll
            for (int j = 0; j < SS; ++j)
                acc = fmaf(cattn[j], bf2f(baseh[(size_t)j*DD]), acc);
            P.c_hist[(size_t)(t+1)*BD + (size_t)b*DD + tid] = acc;
            P.vb[(size_t)b*DD + tid] = acc * P.wra[tid];
            ciw[tid] = acc * P.wwa[tid];
        }
        __syncthreads();
        for (int tp = tid >> 6; tp <= t; tp += 8) {
            const float* ch = P.c_hist + (size_t)tp*BD + (size_t)b*DD;
            float a = 0.f;
            #pragma unroll
            for (int j = 0; j < 8; ++j)
                a = fmaf(ciw[lane + 64*j], ch[lane + 64*j], a);
            for (int off = 32; off; off >>= 1) a += __shfl_xor(a, off, 64);
            if (lane == 0) slog[tp] = a;
        }
        __syncthreads();
        if (tid < 16) {
            float v = (tid <= t) ? slog[tid] + P.bwa[0] : -1e30f;
            float mx = v;
            for (int off = 8; off; off >>= 1) mx = fmaxf(mx, __shfl_xor(mx, off, 16));
            float e = (tid <= t) ? __expf(v - mx) : 0.f;
            float sm = e;
            for (int off = 8; off; off >>= 1) sm += __shfl_xor(sm, off, 16);
            P.sattn[b*16 + tid] = e / sm;
        }
    } else {
        if (P.t == 0) return;
        int gb_ = blockIdx.x - 128;                 // 0..255
        int mt = gb_ >> 2, nc = gb_ & 3;            // 64 m-tiles x 4 panels
        int wv = __builtin_amdgcn_readfirstlane(tid >> 6);
        const int koff = wv * 64;
        const float* mprev = P.m_hist + (size_t)(P.t - 1) * BD;
        const int r0 = mt * 2;

        // ---- phase 1: ex[bb][p] = softmax(rlog[r0+bb]) ----
        #pragma unroll
        for (int bb = 0; bb < 2; ++bb) {
            float v = -1e30f;
            if (tid < PP) {
                const float* rp = P.rlogp + (size_t)(r0 + bb)*2048 + tid;
                float t0 = rp[0]    + rp[256];
                float t1 = rp[512]  + rp[768];
                float t2 = rp[1024] + rp[1280];
                float t3 = rp[1536] + rp[1792];
                v = (t0+t1)+(t2+t3);
            }
            float mx = v;
            for (int off = 32; off; off >>= 1) mx = fmaxf(mx, __shfl_xor(mx, off, 64));
            if (lane == 0 && wv < 4) wred[wv] = mx;
            __syncthreads();
            float gmax = fmaxf(fmaxf(wred[0], wred[1]), fmaxf(wred[2], wred[3]));
            float e = (tid < PP) ? __expf(v - gmax) : 0.f;
            float sm = e;
            for (int off = 32; off; off >>= 1) sm += __shfl_xor(sm, off, 64);
            __syncthreads();
            if (lane == 0 && wv < 4) wred[wv] = sm;
            __syncthreads();
            float inv = 1.f / ((wred[0]+wred[1]) + (wred[2]+wred[3]));
            if (tid < PP) exsh[bb][tid] = e * inv;
            __syncthreads();
        }

        // ---- phase 2: mnw rows into LDS; wave wv covers d = koff+lane ----
        {
            int dd = koff + lane;
            const ushortT* kb0 = P.KBh + ((size_t)(r0+0)*512 + dd)*PP;
            const ushortT* kb1 = P.KBh + ((size_t)(r0+1)*512 + dd)*PP;
            float a0 = 0.f, a1 = 0.f, c0v = 0.f, c1v = 0.f;
            #pragma unroll 4
            for (int p = 0; p < PP; p += 2) {
                a0  = fmaf(exsh[0][p],   bf2f(kb0[p]),   a0);
                a1  = fmaf(exsh[0][p+1], bf2f(kb0[p+1]), a1);
                c0v = fmaf(exsh[1][p],   bf2f(kb1[p]),   c0v);
                c1v = fmaf(exsh[1][p+1], bf2f(kb1[p+1]), c1v);
            }
            mnwsh[0][dd] = a0 + a1;
            mnwsh[1][dd] = c0v + c1v;
        }
        __syncthreads();

        // ---- phase 3: 3-seg K-loop (seg 1 A-operand from LDS) ----
        float ax0 = 0.f, ay0 = 0.f, ax1 = 0.f, ay1 = 0.f;
        {   // seg 0: msa @ WamH
            const float* a = P.msa + (size_t)r0 * 512 + koff;
            const uintT* Wb = (const uintT*)(P.WamH + (size_t)koff * 512 + nc * 128) + lane;
            #pragma unroll 8
            for (int k = 0; k < 64; ++k) {
                uintT w = Wb[(size_t)k * 256];
                float wx = __uint_as_float(w << 16);
                float wy = __uint_as_float(w & 0xFFFF0000u);
                float av0 = a[k], av1 = a[512 + k];
                ax0 = fmaf(av0, wx, ax0); ay0 = fmaf(av0, wy, ay0);
                ax1 = fmaf(av1, wx, ax1); ay1 = fmaf(av1, wy, ay1);
            }
        }
        {   // seg 1: mnw(LDS) @ WAH
            const uintT* Wb = (const uintT*)(P.WAH + (size_t)koff * 512 + nc * 128) + lane;
            #pragma unroll 8
            for (int k = 0; k < 64; ++k) {
                uintT w = Wb[(size_t)k * 256];
                float wx = __uint_as_float(w << 16);
                float wy = __uint_as_float(w & 0xFFFF0000u);
                float av0 = mnwsh[0][koff + k], av1 = mnwsh[1][koff + k];
                ax0 = fmaf(av0, wx, ax0); ay0 = fmaf(av0, wy, ay0);
                ax1 = fmaf(av1, wx, ax1); ay1 = fmaf(av1, wy, ay1);
            }
        }
        {   // seg 2: mprev @ WBH
            const float* a = mprev + (size_t)r0 * 512 + koff;
            const uintT* Wb = (const uintT*)(P.WBH + (size_t)koff * 512 + nc * 128) + lane;
            #pragma unroll 8
            for (int k = 0; k < 64; ++k) {
                uintT w = Wb[(size_t)k * 256];
                float wx = __uint_as_float(w << 16);
                float wy = __uint_as_float(w & 0xFFFF0000u);
                float av0 = a[k], av1 = a[512 + k];
                ax0 = fmaf(av0, wx, ax0); ay0 = fmaf(av0, wy, ay0);
                ax1 = fmaf(av1, wx, ax1); ay1 = fmaf(av1, wy, ay1);
            }
        }
        *(float2*)&red[wv][0][lane*2] = make_float2(ax0, ay0);
        *(float2*)&red[wv][1][lane*2] = make_float2(ax1, ay1);
        __syncthreads();
        if (tid < 256) {
            int mm = tid >> 7, cl = tid & 127;
            float s = 0.f;
            #pragma unroll
            for (int j = 0; j < 8; ++j) s += red[j][mm][cl];
            int row = r0 + mm, col = nc*128 + cl;
            size_t o = (size_t)row*512 + col;
            float v = s + P.b2[col];
            float g = P.gb[o];
            float pv = mprev[o];
            P.dst[o] = g*pv + (1.f - g)*v;
        }
    }
}

// ---------------------------------------------------------------------------
// read1y: block (b, dg). y-slice (64) in LDS (y = (u*mp)@WkbTH + vW), then
// partial rlog over the 64-d slice of bf16 KB.
// ---------------------------------------------------------------------------
__global__ __launch_bounds__(256)
void read1y(const ushortT* __restrict__ KBh, const float* __restrict__ ubuf,
            const float* __restrict__ mp, const ushortT* __restrict__ WkbTh,
            const float* __restrict__ vW, float* __restrict__ rlogp)
{
    int b = blockIdx.x, dg = blockIdx.y, tid = threadIdx.x;
    int lane = tid & 63, w = tid >> 6;
    __shared__ float red[4][64];
    __shared__ float yb[64];
    {
        const float* ur = ubuf + (size_t)b*512;
        const float* mr = mp + (size_t)b*512;
        const ushortT* Wc = WkbTh + dg*64 + lane;
        float s = 0.f;
        for (int k = w*128; k < w*128 + 128; ++k)
            s = fmaf(ur[k]*mr[k], bf2f(Wc[(size_t)k*512]), s);
        red[w][lane] = s;
    }
    __syncthreads();
    if (tid < 64)
        yb[tid] = (red[0][tid]+red[1][tid]) + (red[2][tid]+red[3][tid])
                + vW[(size_t)b*512 + dg*64 + tid];
    __syncthreads();
    float a0=0.f, a1=0.f, a2=0.f, a3=0.f;
    if (tid < PP) {
        const ushortT* kb = KBh + ((size_t)b*512 + dg*64)*PP + tid;
        #pragma unroll 4
        for (int dd = 0; dd < 64; dd += 4) {
            a0 = fmaf(bf2f(kb[(size_t)(dd+0)*PP]), yb[dd+0], a0);
            a1 = fmaf(bf2f(kb[(size_t)(dd+1)*PP]), yb[dd+1], a1);
            a2 = fmaf(bf2f(kb[(size_t)(dd+2)*PP]), yb[dd+2], a2);
            a3 = fmaf(bf2f(kb[(size_t)(dd+3)*PP]), yb[dd+3], a3);
        }
    }
    rlogp[((size_t)b*8 + dg)*256 + tid] = (a0+a1)+(a2+a3);
}

// ---------------------------------------------------------------------------
// setup_misc: one flat dispatch -- weight transposes (768; emit bf16),
// cws transpose -> bf16 (2048), KB bf16 VECTORIZED (6272), hist init (256),
// b2 vecmat (8), fp32->bf16 conversions VECTORIZED (7 x 128).
// ---------------------------------------------------------------------------
struct SetupP {
    const float *Wrm, *Wkb, *cws, *KB, *c0v, *m0v, *bwm;
    const float *Wam, *Wam_bot, *bam, *Wg, *Wm, *Wq, *Wct;
    float *c_hist, *m_hist, *b2;
    ushortT *KBh, *cwsTh, *WamH, *WgH, *WmH, *WqH, *WambH, *WctHt, *WctHb;
    ushortT *WrmTuH, *WrmTvH, *WkbTH;
};

__global__ __launch_bounds__(256)
void setup_misc(SetupP P)
{
    __shared__ float tile[32][33];
    int id = blockIdx.x, tid = threadIdx.x;

    if (id < 768) {            // weight transposes -> bf16
        int which = id >> 8, tj = id & 255;
        const float* src = (which == 0) ? P.Wrm
                         : (which == 1) ? (P.Wrm + 512*512) : P.Wkb;
        ushortT* dst = (which == 0) ? P.WrmTuH
                     : (which == 1) ? P.WrmTvH : P.WkbTH;
        int bx = (tj & 15) * 32, by = (tj >> 4) * 32;
        int tx = tid & 31, ty = tid >> 5;
        #pragma unroll
        for (int i = 0; i < 32; i += 8)
            tile[ty+i][tx] = src[(size_t)(by+ty+i)*512 + bx+tx];
        __syncthreads();
        #pragma unroll
        for (int i = 0; i < 32; i += 8)
            dst[(size_t)(bx+ty+i)*512 + by+tx] = f2bf(tile[tx][ty+i]);
    } else if (id < 2816) {    // cwsTh[b][s][d] = bf16(cws[b][d][s])
        int j = id - 768;
        int b = j >> 4, dc = j & 15;
        const float* src = P.cws + ((size_t)b*DD + dc*32) * SS;
        for (int i = tid; i < 1024; i += 256) {
            int r = i >> 5, s = i & 31;
            if (s < SS) tile[r][s] = src[(size_t)r*SS + s];
        }
        __syncthreads();
        for (int i = tid; i < 1024; i += 256) {
            int s = i >> 5, r = i & 31;
            if (s < SS)
                P.cwsTh[((size_t)b*SS + s)*DD + dc*32 + r] = f2bf(tile[r][s]);
        }
    } else if (id < 9088) {    // KB -> bf16, vectorized 16B/lane
        size_t i = ((size_t)(id - 2816) * 256 + tid) * 8;
        const float4* s4 = (const float4*)(P.KB + i);
        float4 v0 = s4[0], v1 = s4[1];
        uint4 o;
        o.x = pack2bf(v0.x, v0.y);
        o.y = pack2bf(v0.z, v0.w);
        o.z = pack2bf(v1.x, v1.y);
        o.w = pack2bf(v1.z, v1.w);
        *(uint4*)(P.KBh + i) = o;
    } else if (id < 9344) {    // init hist
        int i = (id - 9088) * 256 + tid;
        P.c_hist[i] = P.c0v[i];
        P.m_hist[i] = P.m0v[i];
    } else if (id < 9352) {    // b2 = bwm @ Wam_bot + bam (8 blocks)
        int lane = tid & 63, w = tid >> 6;
        int n = (id - 9344) * 64 + lane;
        float s = 0.f;
        for (int k = w*128; k < w*128 + 128; ++k)
            s = fmaf(P.bwm[k], P.Wam_bot[(size_t)k*512 + n], s);
        __shared__ float red[4][64];
        red[w][lane] = s;
        __syncthreads();
        if (tid < 64) {
            int nn = (id - 9344) * 64 + tid;
            P.b2[nn] = red[0][tid] + red[1][tid] + red[2][tid] + red[3][tid]
                     + P.bam[nn];
        }
    } else {                   // fp32 -> bf16 conversions, vectorized, 7 x 128
        int j = id - 9352;
        int which = j >> 7, blk = j & 127;
        const float* src = (which == 0) ? P.Wam
                         : (which == 1) ? P.Wg
                         : (which == 2) ? P.Wm
                         : (which == 3) ? P.Wq
                         : (which == 4) ? P.Wam_bot
                         : (which == 5) ? P.Wct : (P.Wct + 512*512);
        ushortT* dst = (which == 0) ? P.WamH
                     : (which == 1) ? P.WgH
                     : (which == 2) ? P.WmH
                     : (which == 3) ? P.WqH
                     : (which == 4) ? P.WambH
                     : (which == 5) ? P.WctHt : P.WctHb;
        size_t i = ((size_t)blk * 256 + tid) * 8;
        const float4* s4 = (const float4*)(src + i);
        float4 v0 = s4[0], v1 = s4[1];
        uint4 o;
        o.x = pack2bf(v0.x, v0.y);
        o.y = pack2bf(v0.z, v0.w);
        o.z = pack2bf(v1.x, v1.y);
        o.w = pack2bf(v1.z, v1.w);
        *(uint4*)(dst + i) = o;
    }
}

// ---------------------------------------------------------------------------
extern "C" void kernel_launch(void* const* d_in, const int* in_sizes, int n_in,
                              void* d_out, int out_size, void* d_ws, size_t ws_size,
                              hipStream_t stream)
{
    (void)in_sizes; (void)n_in; (void)out_size; (void)ws_size;
    const float* q   = (const float*)d_in[0];
    const float* cws = (const float*)d_in[1];
    const float* KB  = (const float*)d_in[2];
    const float* c0  = (const float*)d_in[3];
    const float* m0  = (const float*)d_in[4];
    const float* Wq  = (const float*)d_in[5];
    const float* bq  = (const float*)d_in[6];
    const float* Wct = (const float*)d_in[7];
    const float* bct = (const float*)d_in[8];
    const float* wca = (const float*)d_in[9];
    const float* bca = (const float*)d_in[10];
    const float* Wm  = (const float*)d_in[11];
    const float* bm  = (const float*)d_in[12];
    const float* Wkb = (const float*)d_in[13];
    // d_in[14] = bkb : softmax-shift-invariant, dropped
    const float* Wrm = (const float*)d_in[15];
    // d_in[16] = brm, d_in[18] = bra : dropped (softmax-shift-invariant)
    const float* wra = (const float*)d_in[17];
    const float* Wwm = (const float*)d_in[19];
    const float* bwm = (const float*)d_in[20];
    const float* wwa = (const float*)d_in[21];
    const float* bwa = (const float*)d_in[22];
    const float* Wam = (const float*)d_in[23];
    const float* bam = (const float*)d_in[24];
    const float* Wg  = (const float*)d_in[25];
    const float* bg  = (const float*)d_in[26];
    // d_in[27] = steps == 12 (hardcoded TT)

    float* ws      = (float*)d_ws;
    float* c_hist  = ws;              // 13 BD
    float* m_hist  = ws + 13*BD;      // 13 BD
    float* qct     = ws + 26*BD;
    float* q_i     = ws + 27*BD;
    float* cq      = ws + 28*BD;
    float* mp      = ws + 29*BD;
    float* vb      = ws + 30*BD;
    float* ubuf    = ws + 31*BD;
    float* vW      = ws + 32*BD;
    float* gb      = ws + 33*BD;
    float* msa     = ws + 34*BD;
    float* sattn   = ws + 36*BD;      // 2048
    float* rlogp   = ws + 37*BD;      // 4 BD
    ushortT* WkbTH = (ushortT*)(ws + 49*BD);
    float* b2      = ws + 61*BD;      // 512
    ushortT* cwsTh = (ushortT*)(ws + 62*BD);   // 15 BD
    ushortT* KBh   = (ushortT*)(ws + 92*BD);   // 49 BD
    ushortT* WamH  = (ushortT*)(ws + 190*BD);  // 2 BD each below
    ushortT* WAH   = (ushortT*)(ws + 192*BD);
    ushortT* WBH   = (ushortT*)(ws + 194*BD);
    ushortT* WgH   = (ushortT*)(ws + 196*BD);
    ushortT* WmH   = (ushortT*)(ws + 198*BD);
    ushortT* WqH   = (ushortT*)(ws + 200*BD);
    ushortT* WambH = (ushortT*)(ws + 202*BD);
    ushortT* WctHt = (ushortT*)(ws + 204*BD);
    ushortT* WctHb = (ushortT*)(ws + 206*BD);
    ushortT* WrmTuH= (ushortT*)(ws + 208*BD);
    ushortT* WrmTvH= (ushortT*)(ws + 210*BD);

    const float* Wam_bot = Wam + 512*512;
    const float* Wwm_bot = Wwm + 512*512;
    dim3 blk(256);
    GDesc Z = { nullptr,nullptr,nullptr,nullptr,nullptr,nullptr,nullptr,
                1, 6, 0, 0, 0 };

    // ---- setup (3 dispatches) ----
    {
        SetupP S;
        S.Wrm = Wrm; S.Wkb = Wkb; S.cws = cws; S.KB = KB;
        S.c0v = c0; S.m0v = m0; S.bwm = bwm;
        S.Wam = Wam; S.Wam_bot = Wam_bot; S.bam = bam;
        S.Wg = Wg; S.Wm = Wm; S.Wq = Wq; S.Wct = Wct;
        S.c_hist = c_hist; S.m_hist = m_hist; S.b2 = b2;
        S.KBh = KBh; S.cwsTh = cwsTh;
        S.WamH = WamH; S.WgH = WgH; S.WmH = WmH; S.WqH = WqH;
        S.WambH = WambH; S.WctHt = WctHt; S.WctHb = WctHb;
        S.WrmTuH = WrmTuH; S.WrmTvH = WrmTvH; S.WkbTH = WkbTH;
        setup_misc<<<dim3(10248), blk, 0, stream>>>(S);
    }
    {   // WAH = bf16(Wwm_top@WambH) ; WBH = bf16(Wwm_bot@WambH) ;
        // q_i = q@WqH + bq
        GPack pk;
        pk.d[0] = { Wwm, nullptr, WambH, nullptr, nullptr, (float*)WAH,
                    nullptr, 1, 7, 64, 4, 0 };
        pk.d[1] = { Wwm_bot, nullptr, WambH, nullptr, nullptr, (float*)WBH,
                    nullptr, 1, 7, 64, 4, 0 };
        pk.d[2] = { q, nullptr, WqH, nullptr, bq, q_i, nullptr,
                    1, 0, 16, 4, 0 };
        pk.d[3] = Z; pk.d[4] = Z; pk.d[5] = Z;
        gemm4<<<dim3(64,4,3), blk, 0, stream>>>(pk);
    }
    {   // qct = q_i@WctHt + bct ; cq0 = q_i@WctHt + c0@WctHb + bct
        GPack pk;
        pk.d[0] = { q_i, nullptr, WctHt, nullptr, bct, qct, nullptr,
                    1, 0, 16, 4, 0 };
        pk.d[1] = { q_i, c0, WctHt, WctHb, bct, cq, nullptr,
                    2, 0, 16, 4, 0 };
        pk.d[2] = Z; pk.d[3] = Z; pk.d[4] = Z; pk.d[5] = Z;
        gemm4<<<dim3(16,4,2), blk, 0, stream>>>(pk);
    }

    // ---- recurrence: 3 dispatches per step ----
    for (int t = 0; t <= TT; ++t) {
        {   // stepA: control(t) [t<12] || gemmD(t-1)+read2-fused [t>0]
            SP P;
            P.cq = cq; P.cwsTh = cwsTh;
            P.wca = wca; P.bca = bca; P.wra = wra; P.wwa = wwa; P.bwa = bwa;
            P.c_hist = c_hist; P.sattn = sattn; P.vb = vb;
            P.msa = msa; P.gb = gb; P.b2 = b2;
            P.rlogp = rlogp; P.KBh = KBh;
            P.WamH = WamH; P.WAH = WAH; P.WBH = WBH;
            P.m_hist = m_hist;
            P.dst = (t == TT) ? (float*)d_out : (m_hist + (size_t)t * BD);
            P.t = t;
            stepA<<<dim3(384), dim3(512), 0, stream>>>(P);
        }
        if (t == TT) break;

        float* c_i = c_hist + (size_t)(t+1) * BD;
        {   // u || vW || g || cq(t+1) || mp || m_sa
            GPack pk;
            pk.d[0] = { vb, nullptr, WrmTuH, nullptr, nullptr, ubuf, nullptr,
                        1, 6, 16, 4, 0 };
            pk.d[1] = { vb, nullptr, WrmTvH, nullptr, nullptr, vW, nullptr,
                        1, 6, 16, 4, 0 };
            pk.d[2] = { c_i, nullptr, WgH, nullptr, bg, gb, nullptr,
                        1, 1, 16, 4, 0 };
            pk.d[3] = { c_i, nullptr, WctHb, nullptr, nullptr, cq, qct,
                        1, 4, 16, 4, 0 };
            pk.d[4] = { m_hist + (size_t)t * BD, nullptr, WmH, nullptr, bm, mp,
                        nullptr, 1, 0, 16, 4, 0 };
            pk.d[5] = { m_hist, nullptr, nullptr, nullptr, nullptr, msa, sattn,
                        1, 5, 16, 4, t };
            gemm4<<<dim3(16,4,6), blk, 0, stream>>>(pk);
        }
        read1y<<<dim3(BB,8), blk, 0, stream>>>(KBh, ubuf, mp, WkbTH, vW, rlogp);
    }
}

// Round 17
// 745.144 us; speedup vs baseline: 2.5932x; 2.5932x over previous
//
#include <hip/hip_runtime.h>
#include <cstdint>

#define BB 128
#define DD 512
#define SS 30
#define PP 196
#define TT 12
#define BD (BB*DD)

typedef unsigned short ushortT;
typedef unsigned int uintT;

__device__ __forceinline__ float bf2f(ushortT u)
{
    return __uint_as_float(((uintT)u) << 16);
}
__device__ __forceinline__ ushortT f2bf(float f)
{
    uintT b = __float_as_uint(f);
    return (ushortT)((b + 0x7FFFu + ((b >> 16) & 1u)) >> 16);
}
__device__ __forceinline__ uintT pack2bf(float lo, float hi)
{
    return (uintT)f2bf(lo) | ((uintT)f2bf(hi) << 16);
}

// ---------------------------------------------------------------------------
// Unified small GEMM, bf16 weights: out[m0..m0+8, c0..c0+128) =
// epi( sum_p A_p @ W_p ). block 256 (4 waves, wave = K-split 128/part);
// lane covers 2 cols via one uint load (16 FMA/load); A rows uniform scalar;
// LDS reduce. grid (mblk=M/8, nblk=4, z).
// epi: 0 +bias | 1 sigmoid(+bias) | 4 acc+e1[row,col] | 5 m_sa (A0=m_hist,
//      e1=sattn) | 6 raw | 7 raw -> bf16 store into (ushortT*)out
// ---------------------------------------------------------------------------
struct GDesc {
    const float *A0, *A1;
    const ushortT *W0, *W1;
    const float *bias;
    float *out;
    const float *e1;
    int nparts, epi, mblk, nblk, aux;
};
struct GPack { GDesc d[6]; };

__global__ __launch_bounds__(256)
void gemm4(GPack pk)
{
    GDesc d = pk.d[blockIdx.z];
    if ((int)blockIdx.x >= d.mblk || (int)blockIdx.y >= d.nblk) return;
    const int tid  = threadIdx.x;
    const int lane = tid & 63;
    const int wv   = __builtin_amdgcn_readfirstlane(tid >> 6);

    if (d.epi == 5) {   // m_sa for 2 b's: sum_{tp<=aux} sattn[b,tp]*m_hist[tp,b,:]
        int bb = (blockIdx.x * 4 + blockIdx.y) * 2;
        #pragma unroll
        for (int b = bb; b < bb + 2; ++b) {
            const float* sat = d.e1 + b * 16;
            float a0 = 0.f, a1 = 0.f;
            for (int tp = 0; tp <= d.aux; ++tp) {
                float s = sat[tp];
                const float* mh = d.A0 + (size_t)tp * BD + (size_t)b * DD;
                a0 = fmaf(s, mh[tid], a0);
                a1 = fmaf(s, mh[tid + 256], a1);
            }
            d.out[(size_t)b * DD + tid] = a0;
            d.out[(size_t)b * DD + tid + 256] = a1;
        }
        return;
    }

    const int m0 = blockIdx.x * 8;
    const int c0 = blockIdx.y * 128;
    float accx[8], accy[8];
    #pragma unroll
    for (int m = 0; m < 8; ++m) { accx[m] = 0.f; accy[m] = 0.f; }

    for (int p = 0; p < d.nparts; ++p) {
        const float* A = p ? d.A1 : d.A0;
        const ushortT* W = p ? d.W1 : d.W0;
        const float* a = A + (size_t)m0 * 512 + wv * 128;      // uniform (SGPR)
        const uintT* Wb = (const uintT*)(W + (size_t)(wv * 128) * 512 + c0) + lane;
        #pragma unroll 4
        for (int k = 0; k < 128; ++k) {
            uintT w = Wb[(size_t)k * 256];
            float wx = __uint_as_float(w << 16);
            float wy = __uint_as_float(w & 0xFFFF0000u);
            #pragma unroll
            for (int m = 0; m < 8; ++m) {
                float av = a[m * 512 + k];
                accx[m] = fmaf(av, wx, accx[m]);
                accy[m] = fmaf(av, wy, accy[m]);
            }
        }
    }

    __shared__ float red[4][8][128];
    #pragma unroll
    for (int m = 0; m < 8; ++m)
        *(float2*)&red[wv][m][lane * 2] = make_float2(accx[m], accy[m]);
    __syncthreads();

    for (int i = tid; i < 1024; i += 256) {
        int mm = i >> 7, cl = i & 127;
        float s = (red[0][mm][cl] + red[1][mm][cl])
                + (red[2][mm][cl] + red[3][mm][cl]);
        int row = m0 + mm, col = c0 + cl;
        size_t o = (size_t)row * 512 + col;
        if (d.epi == 0)      d.out[o] = s + d.bias[col];
        else if (d.epi == 1) { float v = s + d.bias[col];
                               d.out[o] = 1.f / (1.f + __expf(-v)); }
        else if (d.epi == 4) d.out[o] = s + d.e1[o];
        else if (d.epi == 7) ((ushortT*)d.out)[o] = f2bf(s);
        else                 d.out[o] = s;
    }
}

// ---------------------------------------------------------------------------
// stepA: blocks 0-127 -> control(t) [t<12]; blocks 128-383 -> gemmD(t-1) [t>0]
// gemmD: m_out(t-1) = gate( msa@Wam_top + mnw@WA + mprev@WB + b2 ), K=1536,
// bf16 weights. 2-row m-tile, 128-col panel, 8 waves; wave wv owns k-chunk
// [wv*64,+64) of EACH 512-K segment -- all loop bounds compile-time.
// ---------------------------------------------------------------------------
struct SP {
    const float *cq, *wca, *bca, *wra, *wwa, *bwa;
    const ushortT *cwsTh;
    float *c_hist, *sattn, *vb;
    const float *msa, *mnw, *gb, *b2;
    const ushortT *WamH, *WAH, *WBH;
    float *m_hist, *dst;
    int t;
};

__global__ __launch_bounds__(512)
void stepA(SP P)
{
    const int tid = threadIdx.x;
    const int lane = tid & 63;
    __shared__ float cqw[512], ciw[512];
    __shared__ float clog2[32], cattn[32], slog[16];
    __shared__ float red[8][2][128];

    if ((int)blockIdx.x < 128) {
        if (P.t >= TT) return;
        int b = blockIdx.x, w = tid >> 6, t = P.t;
        cqw[tid] = P.cq[(size_t)b*DD + tid] * P.wca[tid];
        __syncthreads();
        for (int s = w; s < SS; s += 8) {
            const ushortT* row = P.cwsTh + ((size_t)b*SS + s)*DD;
            float a = 0.f;
            #pragma unroll
            for (int j = 0; j < 8; ++j)
                a = fmaf(cqw[lane + 64*j], bf2f(row[lane + 64*j]), a);
            for (int off = 32; off; off >>= 1) a += __shfl_xor(a, off, 64);
            if (lane == 0) clog2[s] = a;
        }
        __syncthreads();
        if (tid < 32) {
            float v = (tid < SS) ? clog2[tid] + P.bca[0] : -1e30f;
            float mx = v;
            for (int off = 16; off; off >>= 1) mx = fmaxf(mx, __shfl_xor(mx, off, 32));
            float e = (tid < SS) ? __expf(v - mx) : 0.f;
            float sm = e;
            for (int off = 16; off; off >>= 1) sm += __shfl_xor(sm, off, 32);
            cattn[tid] = e / sm;
        }
        __syncthreads();
        {   // c_i[d] = sum_s cattn[s] * cwsTh[b][s][d]  (coalesced bf16 rows)
            const ushortT* baseh = P.cwsTh + (size_t)b*SS*DD + tid;
            float acc = 0.f;
            #pragma unroll
            for (int j = 0; j < SS; ++j)
                acc = fmaf(cattn[j], bf2f(baseh[(size_t)j*DD]), acc);
            P.c_hist[(size_t)(t+1)*BD + (size_t)b*DD + tid] = acc;
            P.vb[(size_t)b*DD + tid] = acc * P.wra[tid];
            ciw[tid] = acc * P.wwa[tid];
        }
        __syncthreads();
        for (int tp = tid >> 6; tp <= t; tp += 8) {
            const float* ch = P.c_hist + (size_t)tp*BD + (size_t)b*DD;
            float a = 0.f;
            #pragma unroll
            for (int j = 0; j < 8; ++j)
                a = fmaf(ciw[lane + 64*j], ch[lane + 64*j], a);
            for (int off = 32; off; off >>= 1) a += __shfl_xor(a, off, 64);
            if (lane == 0) slog[tp] = a;
        }
        __syncthreads();
        if (tid < 16) {
            float v = (tid <= t) ? slog[tid] + P.bwa[0] : -1e30f;
            float mx = v;
            for (int off = 8; off; off >>= 1) mx = fmaxf(mx, __shfl_xor(mx, off, 16));
            float e = (tid <= t) ? __expf(v - mx) : 0.f;
            float sm = e;
            for (int off = 8; off; off >>= 1) sm += __shfl_xor(sm, off, 16);
            P.sattn[b*16 + tid] = e / sm;
        }
    } else {
        if (P.t == 0) return;
        int gb_ = blockIdx.x - 128;                 // 0..255
        int mt = gb_ >> 2, nc = gb_ & 3;            // 64 m-tiles x 4 panels
        int wv = __builtin_amdgcn_readfirstlane(tid >> 6);
        const int koff = wv * 64;
        const float* mprev = P.m_hist + (size_t)(P.t - 1) * BD;
        const int r0 = mt * 2;
        float ax0 = 0.f, ay0 = 0.f, ax1 = 0.f, ay1 = 0.f;

        const float* As[3] = { P.msa, P.mnw, mprev };
        const ushortT* Ws[3] = { P.WamH, P.WAH, P.WBH };
        #pragma unroll
        for (int seg = 0; seg < 3; ++seg) {
            const float* a = As[seg] + (size_t)r0 * 512 + koff;
            const uintT* Wb = (const uintT*)(Ws[seg] + (size_t)koff * 512 + nc * 128) + lane;
            #pragma unroll 8
            for (int k = 0; k < 64; ++k) {
                uintT w = Wb[(size_t)k * 256];
                float wx = __uint_as_float(w << 16);
                float wy = __uint_as_float(w & 0xFFFF0000u);
                float av0 = a[k], av1 = a[512 + k];
                ax0 = fmaf(av0, wx, ax0); ay0 = fmaf(av0, wy, ay0);
                ax1 = fmaf(av1, wx, ax1); ay1 = fmaf(av1, wy, ay1);
            }
        }
        *(float2*)&red[wv][0][lane*2] = make_float2(ax0, ay0);
        *(float2*)&red[wv][1][lane*2] = make_float2(ax1, ay1);
        __syncthreads();
        if (tid < 256) {
            int mm = tid >> 7, cl = tid & 127;
            float s = 0.f;
            #pragma unroll
            for (int j = 0; j < 8; ++j) s += red[j][mm][cl];
            int row = r0 + mm, col = nc*128 + cl;
            size_t o = (size_t)row*512 + col;
            float v = s + P.b2[col];
            float g = P.gb[o];
            float pv = mprev[o];
            P.dst[o] = g*pv + (1.f - g)*v;
        }
    }
}

// ---------------------------------------------------------------------------
// read1y: block (b, dg). y-slice (64) in LDS (y = (u*mp)@WkbTH + vW), then
// partial rlog over the 64-d slice of bf16 KB.
// ---------------------------------------------------------------------------
__global__ __launch_bounds__(256)
void read1y(const ushortT* __restrict__ KBh, const float* __restrict__ ubuf,
            const float* __restrict__ mp, const ushortT* __restrict__ WkbTh,
            const float* __restrict__ vW, float* __restrict__ rlogp)
{
    int b = blockIdx.x, dg = blockIdx.y, tid = threadIdx.x;
    int lane = tid & 63, w = tid >> 6;
    __shared__ float red[4][64];
    __shared__ float yb[64];
    {
        const float* ur = ubuf + (size_t)b*512;
        const float* mr = mp + (size_t)b*512;
        const ushortT* Wc = WkbTh + dg*64 + lane;
        float s = 0.f;
        for (int k = w*128; k < w*128 + 128; ++k)
            s = fmaf(ur[k]*mr[k], bf2f(Wc[(size_t)k*512]), s);
        red[w][lane] = s;
    }
    __syncthreads();
    if (tid < 64)
        yb[tid] = (red[0][tid]+red[1][tid]) + (red[2][tid]+red[3][tid])
                + vW[(size_t)b*512 + dg*64 + tid];
    __syncthreads();
    float a0=0.f, a1=0.f, a2=0.f, a3=0.f;
    if (tid < PP) {
        const ushortT* kb = KBh + ((size_t)b*512 + dg*64)*PP + tid;
        #pragma unroll 4
        for (int dd = 0; dd < 64; dd += 4) {
            a0 = fmaf(bf2f(kb[(size_t)(dd+0)*PP]), yb[dd+0], a0);
            a1 = fmaf(bf2f(kb[(size_t)(dd+1)*PP]), yb[dd+1], a1);
            a2 = fmaf(bf2f(kb[(size_t)(dd+2)*PP]), yb[dd+2], a2);
            a3 = fmaf(bf2f(kb[(size_t)(dd+3)*PP]), yb[dd+3], a3);
        }
    }
    rlogp[((size_t)b*8 + dg)*256 + tid] = (a0+a1)+(a2+a3);
}

// ---------------------------------------------------------------------------
// read2: reduce partials -> softmax(196) -> m_new 64-d slice from bf16 KB.
// ---------------------------------------------------------------------------
__global__ __launch_bounds__(256)
void read2(const ushortT* __restrict__ KBh, const float* __restrict__ rlogp,
           float* __restrict__ m_new)
{
    int b = blockIdx.x, dg = blockIdx.y;
    int tid = threadIdx.x, lane = tid & 63, w = tid >> 6;
    __shared__ float ex[256];
    __shared__ float wred[4];

    float v = -1e30f;
    if (tid < PP) {
        const float* rp = rlogp + (size_t)b*2048 + tid;
        float t0 = rp[0]    + rp[256];
        float t1 = rp[512]  + rp[768];
        float t2 = rp[1024] + rp[1280];
        float t3 = rp[1536] + rp[1792];
        v = (t0+t1)+(t2+t3);
    }
    float mx = v;
    for (int off = 32; off; off >>= 1) mx = fmaxf(mx, __shfl_xor(mx, off, 64));
    if (lane == 0) wred[w] = mx;
    __syncthreads();
    float gmax = fmaxf(fmaxf(wred[0], wred[1]), fmaxf(wred[2], wred[3]));
    float e = (tid < PP) ? __expf(v - gmax) : 0.f;
    float sm = e;
    for (int off = 32; off; off >>= 1) sm += __shfl_xor(sm, off, 64);
    __syncthreads();
    if (lane == 0) wred[w] = sm;
    __syncthreads();
    float inv = 1.f / ((wred[0]+wred[1]) + (wred[2]+wred[3]));
    ex[tid] = e * inv;
    __syncthreads();

    #pragma unroll 2
    for (int i = 0; i < 16; ++i) {
        int d = dg*64 + w*16 + i;
        const ushortT* row = KBh + ((size_t)b*512 + d)*PP;
        float a = ex[lane]       * bf2f(row[lane])
                + ex[lane + 64]  * bf2f(row[lane + 64])
                + ex[lane + 128] * bf2f(row[lane + 128]);
        if (lane < PP - 192) a = fmaf(ex[lane + 192], bf2f(row[lane + 192]), a);
        for (int off = 32; off; off >>= 1) a += __shfl_xor(a, off, 64);
        if (lane == 0) m_new[(size_t)b*512 + d] = a;
    }
}

// ---------------------------------------------------------------------------
// setup_misc: one flat dispatch -- weight transposes (768; emit bf16),
// cws transpose -> bf16 (2048), KB bf16 VECTORIZED (6272), hist init (256),
// b2 vecmat (8), fp32->bf16 conversions VECTORIZED (7 x 128).
// ---------------------------------------------------------------------------
struct SetupP {
    const float *Wrm, *Wkb, *cws, *KB, *c0v, *m0v, *bwm;
    const float *Wam, *Wam_bot, *bam, *Wg, *Wm, *Wq, *Wct;
    float *c_hist, *m_hist, *b2;
    ushortT *KBh, *cwsTh, *WamH, *WgH, *WmH, *WqH, *WambH, *WctHt, *WctHb;
    ushortT *WrmTuH, *WrmTvH, *WkbTH;
};

__global__ __launch_bounds__(256)
void setup_misc(SetupP P)
{
    __shared__ float tile[32][33];
    int id = blockIdx.x, tid = threadIdx.x;

    if (id < 768) {            // weight transposes -> bf16
        int which = id >> 8, tj = id & 255;
        const float* src = (which == 0) ? P.Wrm
                         : (which == 1) ? (P.Wrm + 512*512) : P.Wkb;
        ushortT* dst = (which == 0) ? P.WrmTuH
                     : (which == 1) ? P.WrmTvH : P.WkbTH;
        int bx = (tj & 15) * 32, by = (tj >> 4) * 32;
        int tx = tid & 31, ty = tid >> 5;
        #pragma unroll
        for (int i = 0; i < 32; i += 8)
            tile[ty+i][tx] = src[(size_t)(by+ty+i)*512 + bx+tx];
        __syncthreads();
        #pragma unroll
        for (int i = 0; i < 32; i += 8)
            dst[(size_t)(bx+ty+i)*512 + by+tx] = f2bf(tile[tx][ty+i]);
    } else if (id < 2816) {    // cwsTh[b][s][d] = bf16(cws[b][d][s])
        int j = id - 768;
        int b = j >> 4, dc = j & 15;
        const float* src = P.cws + ((size_t)b*DD + dc*32) * SS;
        for (int i = tid; i < 1024; i += 256) {
            int r = i >> 5, s = i & 31;
            if (s < SS) tile[r][s] = src[(size_t)r*SS + s];
        }
        __syncthreads();
        for (int i = tid; i < 1024; i += 256) {
            int s = i >> 5, r = i & 31;
            if (s < SS)
                P.cwsTh[((size_t)b*SS + s)*DD + dc*32 + r] = f2bf(tile[r][s]);
        }
    } else if (id < 9088) {    // KB -> bf16, vectorized 16B/lane
        size_t i = ((size_t)(id - 2816) * 256 + tid) * 8;
        const float4* s4 = (const float4*)(P.KB + i);
        float4 v0 = s4[0], v1 = s4[1];
        uint4 o;
        o.x = pack2bf(v0.x, v0.y);
        o.y = pack2bf(v0.z, v0.w);
        o.z = pack2bf(v1.x, v1.y);
        o.w = pack2bf(v1.z, v1.w);
        *(uint4*)(P.KBh + i) = o;
    } else if (id < 9344) {    // init hist
        int i = (id - 9088) * 256 + tid;
        P.c_hist[i] = P.c0v[i];
        P.m_hist[i] = P.m0v[i];
    } else if (id < 9352) {    // b2 = bwm @ Wam_bot + bam (8 blocks)
        int lane = tid & 63, w = tid >> 6;
        int n = (id - 9344) * 64 + lane;
        float s = 0.f;
        for (int k = w*128; k < w*128 + 128; ++k)
            s = fmaf(P.bwm[k], P.Wam_bot[(size_t)k*512 + n], s);
        __shared__ float red[4][64];
        red[w][lane] = s;
        __syncthreads();
        if (tid < 64) {
            int nn = (id - 9344) * 64 + tid;
            P.b2[nn] = red[0][tid] + red[1][tid] + red[2][tid] + red[3][tid]
                     + P.bam[nn];
        }
    } else {                   // fp32 -> bf16 conversions, vectorized, 7 x 128
        int j = id - 9352;
        int which = j >> 7, blk = j & 127;
        const float* src = (which == 0) ? P.Wam
                         : (which == 1) ? P.Wg
                         : (which == 2) ? P.Wm
                         : (which == 3) ? P.Wq
                         : (which == 4) ? P.Wam_bot
                         : (which == 5) ? P.Wct : (P.Wct + 512*512);
        ushortT* dst = (which == 0) ? P.WamH
                     : (which == 1) ? P.WgH
                     : (which == 2) ? P.WmH
                     : (which == 3) ? P.WqH
                     : (which == 4) ? P.WambH
                     : (which == 5) ? P.WctHt : P.WctHb;
        size_t i = ((size_t)blk * 256 + tid) * 8;
        const float4* s4 = (const float4*)(src + i);
        float4 v0 = s4[0], v1 = s4[1];
        uint4 o;
        o.x = pack2bf(v0.x, v0.y);
        o.y = pack2bf(v0.z, v0.w);
        o.z = pack2bf(v1.x, v1.y);
        o.w = pack2bf(v1.z, v1.w);
        *(uint4*)(dst + i) = o;
    }
}

// ---------------------------------------------------------------------------
extern "C" void kernel_launch(void* const* d_in, const int* in_sizes, int n_in,
                              void* d_out, int out_size, void* d_ws, size_t ws_size,
                              hipStream_t stream)
{
    (void)in_sizes; (void)n_in; (void)out_size; (void)ws_size;
    const float* q   = (const float*)d_in[0];
    const float* cws = (const float*)d_in[1];
    const float* KB  = (const float*)d_in[2];
    const float* c0  = (const float*)d_in[3];
    const float* m0  = (const float*)d_in[4];
    const float* Wq  = (const float*)d_in[5];
    const float* bq  = (const float*)d_in[6];
    const float* Wct = (const float*)d_in[7];
    const float* bct = (const float*)d_in[8];
    const float* wca = (const float*)d_in[9];
    const float* bca = (const float*)d_in[10];
    const float* Wm  = (const float*)d_in[11];
    const float* bm  = (const float*)d_in[12];
    const float* Wkb = (const float*)d_in[13];
    // d_in[14] = bkb : softmax-shift-invariant, dropped
    const float* Wrm = (const float*)d_in[15];
    // d_in[16] = brm, d_in[18] = bra : dropped (softmax-shift-invariant)
    const float* wra = (const float*)d_in[17];
    const float* Wwm = (const float*)d_in[19];
    const float* bwm = (const float*)d_in[20];
    const float* wwa = (const float*)d_in[21];
    const float* bwa = (const float*)d_in[22];
    const float* Wam = (const float*)d_in[23];
    const float* bam = (const float*)d_in[24];
    const float* Wg  = (const float*)d_in[25];
    const float* bg  = (const float*)d_in[26];
    // d_in[27] = steps == 12 (hardcoded TT)

    float* ws      = (float*)d_ws;
    float* c_hist  = ws;              // 13 BD
    float* m_hist  = ws + 13*BD;      // 13 BD
    float* qct     = ws + 26*BD;
    float* q_i     = ws + 27*BD;
    float* cq      = ws + 28*BD;
    float* mp      = ws + 29*BD;
    float* vb      = ws + 30*BD;
    float* ubuf    = ws + 31*BD;
    float* vW      = ws + 32*BD;
    float* gb      = ws + 33*BD;
    float* msa     = ws + 34*BD;
    float* mnw     = ws + 35*BD;
    float* sattn   = ws + 36*BD;      // 2048
    float* rlogp   = ws + 37*BD;      // 4 BD
    ushortT* WkbTH = (ushortT*)(ws + 49*BD);
    float* b2      = ws + 61*BD;      // 512
    ushortT* cwsTh = (ushortT*)(ws + 62*BD);   // 15 BD
    ushortT* KBh   = (ushortT*)(ws + 92*BD);   // 49 BD
    ushortT* WamH  = (ushortT*)(ws + 190*BD);  // 2 BD each below
    ushortT* WAH   = (ushortT*)(ws + 192*BD);
    ushortT* WBH   = (ushortT*)(ws + 194*BD);
    ushortT* WgH   = (ushortT*)(ws + 196*BD);
    ushortT* WmH   = (ushortT*)(ws + 198*BD);
    ushortT* WqH   = (ushortT*)(ws + 200*BD);
    ushortT* WambH = (ushortT*)(ws + 202*BD);
    ushortT* WctHt = (ushortT*)(ws + 204*BD);
    ushortT* WctHb = (ushortT*)(ws + 206*BD);
    ushortT* WrmTuH= (ushortT*)(ws + 208*BD);
    ushortT* WrmTvH= (ushortT*)(ws + 210*BD);

    const float* Wam_bot = Wam + 512*512;
    const float* Wwm_bot = Wwm + 512*512;
    dim3 blk(256);
    GDesc Z = { nullptr,nullptr,nullptr,nullptr,nullptr,nullptr,nullptr,
                1, 6, 0, 0, 0 };

    // ---- setup (3 dispatches) ----
    {
        SetupP S;
        S.Wrm = Wrm; S.Wkb = Wkb; S.cws = cws; S.KB = KB;
        S.c0v = c0; S.m0v = m0; S.bwm = bwm;
        S.Wam = Wam; S.Wam_bot = Wam_bot; S.bam = bam;
        S.Wg = Wg; S.Wm = Wm; S.Wq = Wq; S.Wct = Wct;
        S.c_hist = c_hist; S.m_hist = m_hist; S.b2 = b2;
        S.KBh = KBh; S.cwsTh = cwsTh;
        S.WamH = WamH; S.WgH = WgH; S.WmH = WmH; S.WqH = WqH;
        S.WambH = WambH; S.WctHt = WctHt; S.WctHb = WctHb;
        S.WrmTuH = WrmTuH; S.WrmTvH = WrmTvH; S.WkbTH = WkbTH;
        setup_misc<<<dim3(10248), blk, 0, stream>>>(S);
    }
    {   // WAH = bf16(Wwm_top@WambH) ; WBH = bf16(Wwm_bot@WambH) ;
        // q_i = q@WqH + bq
        GPack pk;
        pk.d[0] = { Wwm, nullptr, WambH, nullptr, nullptr, (float*)WAH,
                    nullptr, 1, 7, 64, 4, 0 };
        pk.d[1] = { Wwm_bot, nullptr, WambH, nullptr, nullptr, (float*)WBH,
                    nullptr, 1, 7, 64, 4, 0 };
        pk.d[2] = { q, nullptr, WqH, nullptr, bq, q_i, nullptr,
                    1, 0, 16, 4, 0 };
        pk.d[3] = Z; pk.d[4] = Z; pk.d[5] = Z;
        gemm4<<<dim3(64,4,3), blk, 0, stream>>>(pk);
    }
    {   // qct = q_i@WctHt + bct ; cq0 = q_i@WctHt + c0@WctHb + bct
        GPack pk;
        pk.d[0] = { q_i, nullptr, WctHt, nullptr, bct, qct, nullptr,
                    1, 0, 16, 4, 0 };
        pk.d[1] = { q_i, c0, WctHt, WctHb, bct, cq, nullptr,
                    2, 0, 16, 4, 0 };
        pk.d[2] = Z; pk.d[3] = Z; pk.d[4] = Z; pk.d[5] = Z;
        gemm4<<<dim3(16,4,2), blk, 0, stream>>>(pk);
    }

    // ---- recurrence: 4 dispatches per step ----
    for (int t = 0; t <= TT; ++t) {
        {   // stepA: control(t) [t<12] || gemmD(t-1) [t>0]
            SP P;
            P.cq = cq; P.cwsTh = cwsTh;
            P.wca = wca; P.bca = bca; P.wra = wra; P.wwa = wwa; P.bwa = bwa;
            P.c_hist = c_hist; P.sattn = sattn; P.vb = vb;
            P.msa = msa; P.mnw = mnw; P.gb = gb; P.b2 = b2;
            P.WamH = WamH; P.WAH = WAH; P.WBH = WBH;
            P.m_hist = m_hist;
            P.dst = (t == TT) ? (float*)d_out : (m_hist + (size_t)t * BD);
            P.t = t;
            stepA<<<dim3(384), dim3(512), 0, stream>>>(P);
        }
        if (t == TT) break;

        float* c_i = c_hist + (size_t)(t+1) * BD;
        {   // u || vW || g || cq(t+1) || mp || m_sa
            GPack pk;
            pk.d[0] = { vb, nullptr, WrmTuH, nullptr, nullptr, ubuf, nullptr,
                        1, 6, 16, 4, 0 };
            pk.d[1] = { vb, nullptr, WrmTvH, nullptr, nullptr, vW, nullptr,
                        1, 6, 16, 4, 0 };
            pk.d[2] = { c_i, nullptr, WgH, nullptr, bg, gb, nullptr,
                        1, 1, 16, 4, 0 };
            pk.d[3] = { c_i, nullptr, WctHb, nullptr, nullptr, cq, qct,
                        1, 4, 16, 4, 0 };
            pk.d[4] = { m_hist + (size_t)t * BD, nullptr, WmH, nullptr, bm, mp,
                        nullptr, 1, 0, 16, 4, 0 };
            pk.d[5] = { m_hist, nullptr, nullptr, nullptr, nullptr, msa, sattn,
                        1, 5, 16, 4, t };
            gemm4<<<dim3(16,4,6), blk, 0, stream>>>(pk);
        }
        read1y<<<dim3(BB,8), blk, 0, stream>>>(KBh, ubuf, mp, WkbTH, vW, rlogp);
        read2<<<dim3(BB,8), blk, 0, stream>>>(KBh, rlogp, mnw);
    }
}